// Round 13
// baseline (349.382 us; speedup 1.0000x reference)
//
#include <hip/hip_runtime.h>
#include <math.h>

// Problem constants
#define BZ 2
#define HH 56
#define WW 56
#define LL 3136      // 56*56
#define CC 96        // DIM
#define DI 192       // DINNER
#define NS 16        // DSTATE
#define RR 6         // DTRANK
#define NT 49        // LL/64
#define NCH 98       // scan chunks (32 positions each)
#define CH 32        // chunk length

// Merged-launch block counts
#define NBLK_K1A 2352      // (BZ*LL*CC)/256
#define NBLK_K2  784       // NT*8*BZ
#define NBLK_K0  120       // (CC*DI + 4*DI*NS)/256
#define NBLK_K1B 392       // NT*4*BZ
#define NBLK_K3  768       // BZ*DI*2

// Workspace layout (floats)
#define OFF_CONV   0
#define OFF_XMRAW  602112
#define OFF_Z      1806336
#define OFF_V1     3010560
#define OFF_V2     4214784
#define OFF_DT     5419008
#define OFF_BS     10235904
#define OFF_CS     10637312
#define OFF_Y      11038720
#define OFF_Y13    15855616
#define OFF_T      18264064
#define OFF_W2     19468288
// total 19486720 floats = ~78 MB

__device__ __forceinline__ float softplusf(float x) {
    if (x > 20.f) return x;
    return log1pf(__expf(x));
}

// ---------------- kA: merged k1a (dwconv+bn1+relu) | k2 (LN+in_proj) | k0 (prep) -------
__global__ __launch_bounds__(256) void kA(const float* __restrict__ x,
    const float* __restrict__ dw_w, const float* __restrict__ dw_b,
    const float* __restrict__ bn1_g, const float* __restrict__ bn1_b,
    const float* __restrict__ bn1_m, const float* __restrict__ bn1_v,
    const float* __restrict__ ln_g, const float* __restrict__ ln_b,
    const float* __restrict__ ipw,
    const float* __restrict__ fus_w, const float* __restrict__ opw,
    const float* __restrict__ A_logs,
    float* __restrict__ cbuf, float* __restrict__ xm_raw, float* __restrict__ z_buf,
    float* __restrict__ W2, float* __restrict__ negA) {
    int bx = blockIdx.x;
    if (bx < NBLK_K1A) {
        // ---- k1a body ----
        int i = bx * 256 + threadIdx.x;
        if (i >= BZ * LL * CC) return;
        int c = i % CC;
        int bl = i / CC;
        int l = bl % LL, b = bl / LL;
        int h = l / WW, w = l % WW;
        float acc = dw_b[c];
        #pragma unroll
        for (int dy = -1; dy <= 1; ++dy) {
            int hh = h + dy; if (hh < 0 || hh >= HH) continue;
            #pragma unroll
            for (int dx = -1; dx <= 1; ++dx) {
                int ww = w + dx; if (ww < 0 || ww >= WW) continue;
                acc += x[((b * HH + hh) * WW + ww) * CC + c] * dw_w[c * 9 + (dy + 1) * 3 + (dx + 1)];
            }
        }
        float inv = rsqrtf(bn1_v[c] + 1e-5f);
        float v = (acc - bn1_m[c]) * inv * bn1_g[c] + bn1_b[c];
        cbuf[i] = fmaxf(v, 0.f);
    } else if (bx < NBLK_K1A + NBLK_K2) {
        // ---- k2 body ----
        int r = bx - NBLK_K1A;
        int tile = r % NT;
        int og = (r / NT) % 8;
        int b = r / (NT * 8);
        int t0 = tile * 64;
        int lane = threadIdx.x & 63;
        int wv = threadIdx.x >> 6;
        int wvu = __builtin_amdgcn_readfirstlane(wv);
        __shared__ float xt[64 * 97];      // [p][c]
        __shared__ float xn[96 * 65];      // [c][p] normalized
        __shared__ float ps[4][64], ps2[4][64];
        const float* xb = x + (b * LL + t0) * CC;
        for (int e = threadIdx.x; e < 64 * CC; e += 256) {
            int p = e / CC, c = e % CC;
            xt[p * 97 + c] = xb[e];
        }
        __syncthreads();
        float s = 0.f, s2 = 0.f;
        #pragma unroll
        for (int j = 0; j < 24; ++j) {
            float v = xt[lane * 97 + wvu * 24 + j];
            s += v; s2 += v * v;
        }
        ps[wv][lane] = s; ps2[wv][lane] = s2;
        __syncthreads();
        float st = 0.f, st2 = 0.f;
        #pragma unroll
        for (int i = 0; i < 4; ++i) { st += ps[i][lane]; st2 += ps2[i][lane]; }
        float m = st * (1.f / 96.f);
        float inv = rsqrtf(st2 * (1.f / 96.f) - m * m + 1e-5f);
        #pragma unroll
        for (int j = 0; j < 24; ++j) {
            int c = wvu * 24 + j;
            xn[c * 65 + lane] = (xt[lane * 97 + c] - m) * inv * ln_g[c] + ln_b[c];
        }
        __syncthreads();
        float acc[12];
        #pragma unroll
        for (int j = 0; j < 12; ++j) acc[j] = 0.f;
        int o0 = og * 48 + wvu * 12;
        const float* wbase = ipw + o0 * CC;       // uniform -> s_load
        for (int c = 0; c < CC; ++c) {
            float xv = xn[c * 65 + lane];
            #pragma unroll
            for (int j = 0; j < 12; ++j)
                acc[j] += xv * wbase[j * CC + c];
        }
        int p = t0 + lane;
        #pragma unroll
        for (int j = 0; j < 12; ++j) {
            int out = o0 + j;
            if (out < DI) xm_raw[(b * DI + out) * LL + p] = acc[j];
            else          z_buf[(b * DI + (out - DI)) * LL + p] = acc[j];
        }
    } else {
        // ---- k0 body ----
        int i = (bx - NBLK_K1A - NBLK_K2) * 256 + threadIdx.x;
        if (i < CC * DI) {
            int o = i / DI, d = i % DI;
            float acc = 0.f;
            for (int j = 0; j < CC; ++j)
                acc += fus_w[o * DI + CC + j] * opw[j * DI + d];
            W2[i] = acc;
        } else if (i < CC * DI + 4 * DI * NS) {
            int j = i - CC * DI;
            negA[j] = -__expf(A_logs[j]);
        }
    }
}

// ---------------- kB: merged k1b (pw 1x1 + bn2) | k3 (dwconv+SiLU -> v1,v2) -----------
__global__ __launch_bounds__(256) void kB(const float* __restrict__ cbuf,
    const float* __restrict__ pw_w, const float* __restrict__ pw_b,
    const float* __restrict__ bn2_g, const float* __restrict__ bn2_b,
    const float* __restrict__ bn2_m, const float* __restrict__ bn2_v,
    const float* __restrict__ xm_raw,
    const float* __restrict__ conv_w, const float* __restrict__ conv_b,
    float* __restrict__ conv_out, float* __restrict__ v1, float* __restrict__ v2) {
    int bx = blockIdx.x;
    if (bx < NBLK_K1B) {
        // ---- k1b body ----
        int tile = bx % NT;
        int og = (bx / NT) % 4;
        int b = bx / (NT * 4);
        int t0 = tile * 64;
        int lane = threadIdx.x & 63;
        int wvu = __builtin_amdgcn_readfirstlane(threadIdx.x >> 6);
        __shared__ float ct[CC * 65];      // [c][p]
        __shared__ float res[64 * 25];     // [p][24 outs + pad]
        const float* cb = cbuf + (b * LL + t0) * CC;
        for (int e = threadIdx.x; e < 64 * CC; e += 256) {
            int p = e / CC, c = e % CC;
            ct[c * 65 + p] = cb[e];
        }
        __syncthreads();
        int o0 = og * 24 + wvu * 6;
        float acc[6];
        const float* pb = pw_b + o0;
        #pragma unroll
        for (int j = 0; j < 6; ++j) acc[j] = pb[j];
        const float* wb = pw_w + o0 * CC;              // uniform -> s_load
        for (int c = 0; c < CC; ++c) {
            float xv = ct[c * 65 + lane];
            #pragma unroll
            for (int j = 0; j < 6; ++j)
                acc[j] += xv * wb[j * CC + c];
        }
        #pragma unroll
        for (int j = 0; j < 6; ++j) {
            int o = o0 + j;
            float inv = rsqrtf(bn2_v[o] + 1e-5f);
            res[lane * 25 + wvu * 6 + j] = (acc[j] - bn2_m[o]) * inv * bn2_g[o] + bn2_b[o];
        }
        __syncthreads();
        float* ob = conv_out + (b * LL + t0) * CC + og * 24;
        for (int e = threadIdx.x; e < 64 * 24; e += 256) {
            int pl = e / 24, o = e % 24;
            ob[pl * CC + o] = res[pl * 25 + o];
        }
    } else {
        // ---- k3 body ----
        int r = bx - NBLK_K1B;
        int bd = r % (BZ * DI);
        int half = r / (BZ * DI);
        int d = bd % DI;
        int h0 = half * 28;
        __shared__ float tile3[28 * 57];
        const float* src = xm_raw + bd * LL;
        float wloc[9];
        #pragma unroll
        for (int i = 0; i < 9; ++i) wloc[i] = conv_w[d * 9 + i];
        float bias = conv_b[d];
        for (int e = threadIdx.x; e < 28 * WW; e += 256) {
            int hl = e / WW, w = e % WW;
            int h = h0 + hl;
            float acc = bias;
            #pragma unroll
            for (int dy = -1; dy <= 1; ++dy) {
                int hh = h + dy; if (hh < 0 || hh >= HH) continue;
                #pragma unroll
                for (int dx = -1; dx <= 1; ++dx) {
                    int ww = w + dx; if (ww < 0 || ww >= WW) continue;
                    acc += src[hh * WW + ww] * wloc[(dy + 1) * 3 + (dx + 1)];
                }
            }
            float sig = 1.f / (1.f + __expf(-acc));
            float v = acc * sig;
            v1[bd * LL + h * WW + w] = v;
            tile3[hl * 57 + w] = v;
        }
        __syncthreads();
        for (int e = threadIdx.x; e < 28 * WW; e += 256) {
            int w = e / 28, hl = e % 28;
            v2[bd * LL + w * HH + h0 + hl] = tile3[hl * 57 + w];
        }
    }
}

// ---------------- K4a: x_proj — 4-wave blocks, no LDS, 10 rows/wave ----------------
__global__ __launch_bounds__(256) void k4a_xproj(const float* __restrict__ v1,
    const float* __restrict__ v2, const float* __restrict__ xpw,
    float* __restrict__ dtr_g, float* __restrict__ B_s, float* __restrict__ C_s) {
    int tile = blockIdx.x;
    int k = blockIdx.y, b = blockIdx.z;
    int lane = threadIdx.x & 63;
    int wvu = __builtin_amdgcn_readfirstlane(threadIdx.x >> 6);
    int t0 = tile * 64;
    int r0 = wvu * 10; if (r0 > 28) r0 = 28;
    const float* src = ((k & 1) == 0 ? v1 : v2) + b * DI * LL + t0;
    float acc[10];
    #pragma unroll
    for (int i = 0; i < 10; ++i) acc[i] = 0.f;
    const float* wbase = xpw + (k * 38 + r0) * DI;   // uniform -> s_load
    for (int d = 0; d < DI; ++d) {
        float xv = src[d * LL + lane];
        #pragma unroll
        for (int i = 0; i < 10; ++i)
            acc[i] += xv * wbase[i * DI + d];
    }
    int bk = b * 4 + k;
    int p = t0 + lane;
    #pragma unroll
    for (int i = 0; i < 10; ++i) {
        int c = r0 + i;
        if (c < RR) {
            dtr_g[(bk * RR + c) * LL + p] = acc[i];
        } else if (c < RR + NS) {
            B_s[(bk * NS + (c - RR)) * LL + p] = acc[i];
        } else {
            C_s[(bk * NS + (c - RR - NS)) * LL + p] = acc[i];
        }
    }
}

// ---------------- K4b: dt_proj + softplus (streaming write) ----------------
__global__ __launch_bounds__(256) void k4b_dt(const float* __restrict__ dtr_g,
    const float* __restrict__ dtw, const float* __restrict__ dtb,
    float* __restrict__ dt_s) {
    int t0 = blockIdx.x * 64;
    int k = blockIdx.y, b = blockIdx.z;
    int lane = threadIdx.x & 63;
    int wvu = __builtin_amdgcn_readfirstlane(threadIdx.x >> 6);
    int bk = b * 4 + k;
    int p = t0 + lane;
    float r[RR];
    #pragma unroll
    for (int i = 0; i < RR; ++i) r[i] = dtr_g[(bk * RR + i) * LL + p];
    for (int i = 0; i < 48; ++i) {
        int d = wvu * 48 + i;
        float a = dtb[k * DI + d];
        const float* wr = dtw + (k * DI + d) * RR;   // uniform -> s_load
        #pragma unroll
        for (int q = 0; q < RR; ++q)
            a += r[q] * wr[q];
        dt_s[(bk * DI + d) * LL + p] = softplusf(a);
    }
}

// ---------------- K5a: scan phase 1 — streamed dt, 1 chunk/block ------
// y-flush reverted to SCALAR stores (R0 pattern): one instruction = 2 rows x 32
// consecutive lanes = full 128B segments. R0 measured WRITE 28.8 MB (no
// amplification); the R1+ float4 flush correlated with 60.5 MB (2.05x). This
// round isolates that variable. Arithmetic bit-identical.
__global__ __launch_bounds__(128, 4) void k5a_scan(const float* __restrict__ dt_s,
    const float* __restrict__ B_s, const float* __restrict__ C_s,
    const float* __restrict__ v1, const float* __restrict__ v2,
    const float* __restrict__ A_logs, float* __restrict__ y_scan,
    float* __restrict__ hl_buf, float* __restrict__ Tbuf) {
    int bx = blockIdx.x;
    int dg = bx % 3, c = bx / 3;
    int k = blockIdx.y, b = blockIdx.z;
    int bk = b * 4 + k;
    int tid = threadIdx.x;
    int lane = tid & 63;
    int wvu = __builtin_amdgcn_readfirstlane(tid >> 6);   // n-half: 0 or 1
    int d0 = dg * 64, d = d0 + lane;
    bool fwd = (k < 2);
    int s0 = fwd ? c * CH : (LL - (c + 1) * CH);
    __shared__ float dtl[64 * 32];                 // [row][ s ^ (row&31) ]
    __shared__ float ul[64 * 32];                  // du = dt*u, same swizzle
    __shared__ alignas(16) float bc[32 * 32];      // [s][ n ^ ((s&7)<<2) ]
    float Ae[8];
    const float* ap = A_logs + (k * DI + d) * NS + wvu * 8;
    #pragma unroll
    for (int n = 0; n < 8; ++n) Ae[n] = -__expf(ap[n]) * 1.442695040888963f;
    const float* dtp = dt_s + (bk * DI + d0) * LL + s0;
    const float* up  = ((k & 1) == 0 ? v1 : v2) + (b * DI + d0) * LL + s0;
    // ---- stage dt & du: float4 global loads, swizzled scalar LDS writes ----
    #pragma unroll
    for (int q = 0; q < 4; ++q) {
        int e = q * 128 + tid;          // 0..511
        int row = e >> 3;               // 0..63
        int p4 = (e & 7) << 2;          // 0,4,...,28
        float4 dv = *(const float4*)(dtp + row * LL + p4);
        float4 uv = *(const float4*)(up + row * LL + p4);
        float dvv[4] = {dv.x, dv.y, dv.z, dv.w};
        float uvv[4] = {uv.x, uv.y, uv.z, uv.w};
        int rsw = row & 31;
        #pragma unroll
        for (int t = 0; t < 4; ++t) {
            int s = fwd ? (p4 + t) : (31 - (p4 + t));
            dtl[row * 32 + (s ^ rsw)] = dvv[t];
            ul [row * 32 + (s ^ rsw)] = dvv[t] * uvv[t];
        }
    }
    // ---- stage B/C ----
    #pragma unroll
    for (int q = 0; q < 2; ++q) {
        int e = q * 128 + tid;          // 0..255
        int row = e >> 3;               // 0..31 (B: 0..15, C: 16..31)
        int p4 = (e & 7) << 2;
        const float* src = (row < 16 ? B_s + (bk * NS + row) * LL
                                     : C_s + (bk * NS + (row - 16)) * LL) + s0 + p4;
        float4 v = *(const float4*)src;
        float vv[4] = {v.x, v.y, v.z, v.w};
        #pragma unroll
        for (int t = 0; t < 4; ++t) {
            int s = fwd ? (p4 + t) : (31 - (p4 + t));
            bc[s * 32 + (row ^ ((s & 7) << 2))] = vv[t];
        }
    }
    __syncthreads();
    float h[8];
    #pragma unroll
    for (int n = 0; n < 8; ++n) h[n] = 0.f;
    float cum = 0.f;
    int lbase = lane * 32;
    int lsw = lane & 31;
    int w8 = wvu * 8;
    #pragma unroll
    for (int seg = 0; seg < 4; ++seg) {
        float yv_[8];
        #pragma unroll
        for (int jj = 0; jj < 8; ++jj) {
            int j = seg * 8 + jj;
            float dtv = dtl[lbase + (j ^ lsw)];
            float du  = ul [lbase + (j ^ lsw)];
            cum += dtv;
            int cswz = (j & 7) << 2;
            const float* rb0 = &bc[j * 32 + ( w8       ^ cswz)];
            const float* rb1 = &bc[j * 32 + ((w8 +  4) ^ cswz)];
            const float* rc0 = &bc[j * 32 + ((w8 + 16) ^ cswz)];
            const float* rc1 = &bc[j * 32 + ((w8 + 20) ^ cswz)];
            float4 b0 = *(const float4*)rb0, b1 = *(const float4*)rb1;
            float4 c0 = *(const float4*)rc0, c1 = *(const float4*)rc1;
            float bv[8] = {b0.x, b0.y, b0.z, b0.w, b1.x, b1.y, b1.z, b1.w};
            float cv[8] = {c0.x, c0.y, c0.z, c0.w, c1.x, c1.y, c1.z, c1.w};
            float y = 0.f;
            #pragma unroll
            for (int n = 0; n < 8; ++n) {
                h[n] = exp2f(dtv * Ae[n]) * h[n] + du * bv[n];
                y += h[n] * cv[n];
            }
            yv_[jj] = y;
        }
        // slots seg*8..seg*8+7 are dead once BOTH waves passed them
        __syncthreads();
        float* dst = (wvu == 0) ? dtl : ul;
        #pragma unroll
        for (int jj = 0; jj < 8; ++jj) {
            int j = seg * 8 + jj;
            dst[lbase + (j ^ lsw)] = yv_[jj];
        }
    }
    __syncthreads();
    // ---- flush y: scalar stores, 2 rows x 32 consecutive lanes per instruction ----
    float* yp = y_scan + (bk * DI + d0) * LL + s0;
    int pr = tid >> 5, pc = tid & 31;                 // pr 0..3
    int sg = fwd ? pc : (31 - pc);                    // scan-order slot of global pos pc
    #pragma unroll
    for (int i = 0; i < 16; ++i) {
        int row = i * 4 + pr;
        int rsw = row & 31;
        yp[row * LL + pc] = dtl[row * 32 + (sg ^ rsw)] + ul[row * 32 + (sg ^ rsw)];
    }
    // hlast: each wave owns its 8 n-states
    float4* hp4 = (float4*)(hl_buf + (bk * NCH + c) * (DI * NS) + d * NS + wvu * 8);
    hp4[0] = make_float4(h[0], h[1], h[2], h[3]);
    hp4[1] = make_float4(h[4], h[5], h[6], h[7]);
    if (wvu == 0) Tbuf[(bk * NCH + c) * DI + d] = cum;
}

// ---------------- K5c: scan phase 2 — serial chunk combine, prefetch depth 8 ----------
__global__ __launch_bounds__(64) void k5c_comb(float* __restrict__ hl_buf,
    const float* __restrict__ Tbuf, const float* __restrict__ negA) {
    int dg = blockIdx.x, k = blockIdx.y, b = blockIdx.z;
    int lane = threadIdx.x, dl = lane >> 4, n = lane & 15;
    int d = dg * 4 + dl;
    int bk = b * 4 + k;
    const int HS = DI * NS;
    float Av = negA[(k * DI + d) * NS + n];
    float* hp = hl_buf + (bk * NCH) * HS + dg * 64 + lane;
    const float* Tp = Tbuf + (bk * NCH) * DI + d;
    float hl[8], T[8];
    #pragma unroll
    for (int i = 0; i < 8; ++i) { hl[i] = hp[i * HS]; T[i] = Tp[i * DI]; }
    float H = 0.f;
    for (int cb = 0; cb < 96; cb += 8) {
        #pragma unroll
        for (int i = 0; i < 8; ++i) {
            int c = cb + i;
            float hlv = hl[i], Tv = T[i];
            int nc = c + 8;
            if (nc < NCH) { hl[i] = hp[nc * HS]; T[i] = Tp[nc * DI]; }
            hp[c * HS] = H;
            H = hlv + __expf(Av * Tv) * H;
        }
    }
    hp[96 * HS] = H;
    H = hl[0] + __expf(Av * T[0]) * H;
    hp[97 * HS] = H;
}

// ---------------- K5d: scan phase 3 — parallel correction, d-split x4 ----------
__global__ __launch_bounds__(256) void k5d_corr(const float* __restrict__ dtr_g,
    const float* __restrict__ dtw, const float* __restrict__ dtb,
    const float* __restrict__ C_s, const float* __restrict__ hin,
    const float* __restrict__ negA, float* __restrict__ y_scan) {
    int t  = blockIdx.x % (NCH - 1);
    int ds = blockIdx.x / (NCH - 1);   // 0..3 d-split
    int k = blockIdx.y, b = blockIdx.z;
    bool fwd = (k < 2);
    int c  = fwd ? (t + 1) : (NCH - 1 - t);
    int s0 = fwd ? (t + 1) * CH : t * CH;
    int p32 = threadIdx.x & 31, sl = threadIdx.x >> 5;
    int bk = b * 4 + k;
    __shared__ float c_l[16 * 33];
    for (int e = threadIdx.x; e < 16 * CH; e += 256) {
        int n = e >> 5, s = e & 31;
        c_l[n * 33 + s] = C_s[(bk * NS + n) * LL + s0 + s];
    }
    const float* rp = dtr_g + (bk * RR) * LL + s0 + p32;
    float r[RR];
    #pragma unroll
    for (int q = 0; q < RR; ++q) r[q] = rp[q * LL];
    __syncthreads();
    for (int j = 0; j < 6; ++j) {
        int d = ds * 48 + sl * 6 + j;
        int dd = k * DI + d;
        const float* wr = dtw + dd * RR;
        float a = dtb[dd];
        #pragma unroll
        for (int q = 0; q < RR; ++q)
            a += r[q] * wr[q];
        float dtv = softplusf(a);
        float cum = dtv;
        if (fwd) {
            #pragma unroll
            for (int off = 1; off < 32; off <<= 1) {
                float o = __shfl_up(cum, off, 32);
                if (p32 >= off) cum += o;
            }
        } else {
            #pragma unroll
            for (int off = 1; off < 32; off <<= 1) {
                float o = __shfl_down(cum, off, 32);
                if (p32 < 32 - off) cum += o;
            }
        }
        const float* hp = hin + (bk * NCH + c) * (DI * NS) + d * 16;
        const float* ap = negA + (k * DI + d) * NS;
        float4 h0 = *(const float4*)(hp);
        float4 h1 = *(const float4*)(hp + 4);
        float4 h2 = *(const float4*)(hp + 8);
        float4 h3 = *(const float4*)(hp + 12);
        float4 a0 = *(const float4*)(ap);
        float4 a1 = *(const float4*)(ap + 4);
        float4 a2 = *(const float4*)(ap + 8);
        float4 a3 = *(const float4*)(ap + 12);
        float hv[16] = {h0.x, h0.y, h0.z, h0.w, h1.x, h1.y, h1.z, h1.w,
                        h2.x, h2.y, h2.z, h2.w, h3.x, h3.y, h3.z, h3.w};
        float av[16] = {a0.x, a0.y, a0.z, a0.w, a1.x, a1.y, a1.z, a1.w,
                        a2.x, a2.y, a2.z, a2.w, a3.x, a3.y, a3.z, a3.w};
        float acc = 0.f;
        #pragma unroll
        for (int n = 0; n < 16; ++n) {
            acc += c_l[n * 33 + p32] * __expf(av[n] * cum) * hv[n];
        }
        y_scan[(bk * DI + d) * LL + s0 + p32] += acc;
    }
}

// ---------------- K5b: transpose y for k=1,3 (coalesced both ways via LDS tile) -------
__global__ __launch_bounds__(256) void k5b_tr(const float* __restrict__ y_scan,
                                              float* __restrict__ y13t) {
    int idx = blockIdx.x;
    int d = idx % DI;
    int bk = idx / DI;
    int kk = bk % 2, b = bk / 2;
    int k = (kk == 0) ? 1 : 3;
    __shared__ float tile[HH * 57];
    const float* src = y_scan + ((b * 4 + k) * DI + d) * LL;
    for (int e = threadIdx.x; e < LL; e += 256) {
        int w = e / HH, h = e % HH;
        tile[h * 57 + w] = src[e];
    }
    __syncthreads();
    float* dst = y13t + idx * LL;
    for (int e = threadIdx.x; e < LL; e += 256) {
        int h = e / WW, w = e % WW;
        dst[e] = tile[h * 57 + w];
    }
}

// ---------------- K6: fused gather + out_norm + gate + fus-matmul + LN + residual ------
__global__ __launch_bounds__(256) void k6_fused(const float* __restrict__ y_scan,
    const float* __restrict__ y13t, const float* __restrict__ v1,
    const float* __restrict__ z_buf, const float* __restrict__ Ds,
    const float* __restrict__ ong, const float* __restrict__ onb,
    const float* __restrict__ W2, const float* __restrict__ fus_w,
    const float* __restrict__ fus_b, const float* __restrict__ flg,
    const float* __restrict__ flb, const float* __restrict__ conv_out,
    const float* __restrict__ x, float* __restrict__ out) {
    int t0 = blockIdx.x * 8;
    int b = blockIdx.y;
    int tid = threadIdx.x;
    int p8 = tid & 7, sl = tid >> 3;   // sl 0..31
    int p = t0 + p8;
    __shared__ float yv[DI * 9];       // val -> (in place) gated t, [d][p8+pad]
    __shared__ float ct[CC * 9];       // conv_out [c][p8+pad]
    __shared__ float res[8 * 97];      // normalized fused output [p8][o]
    __shared__ float ps[32][8], ps2[32][8];
    // stage conv_out (for phase 2)
    const float* cb = conv_out + (b * LL + t0) * CC;
    for (int e = tid; e < 8 * CC; e += 256) {
        int pp = e / CC, c = e % CC;
        ct[c * 9 + pp] = cb[e];
    }
    // ---- phase 1: gather 4 dirs + D*u ----
    float s = 0.f, s2 = 0.f;
    for (int j = 0; j < 6; ++j) {
        int d = sl * 6 + j;
        float dsum = Ds[d] + Ds[DI + d] + Ds[2 * DI + d] + Ds[3 * DI + d];
        float val = y_scan[((b * 4 + 0) * DI + d) * LL + p]
                  + y_scan[((b * 4 + 2) * DI + d) * LL + p]
                  + y13t[((b * 2 + 0) * DI + d) * LL + p]
                  + y13t[((b * 2 + 1) * DI + d) * LL + p]
                  + v1[(b * DI + d) * LL + p] * dsum;
        yv[d * 9 + p8] = val;
        s += val; s2 += val * val;
    }
    ps[sl][p8] = s; ps2[sl][p8] = s2;
    __syncthreads();
    float st = 0.f, st2 = 0.f;
    #pragma unroll
    for (int i = 0; i < 32; ++i) { st += ps[i][p8]; st2 += ps2[i][p8]; }
    float m = st * (1.f / 192.f);
    float inv = rsqrtf(st2 * (1.f / 192.f) - m * m + 1e-5f);
    for (int j = 0; j < 6; ++j) {
        int d = sl * 6 + j;
        float val = (yv[d * 9 + p8] - m) * inv * ong[d] + onb[d];
        float zz = z_buf[(b * DI + d) * LL + p];
        float sig = 1.f / (1.f + __expf(-zz));
        yv[d * 9 + p8] = val * zz * sig;       // gated t, in place
    }
    __syncthreads();
    // ---- phase 2: fused matmul (t@W2 | conv_out@fus_w[:96]) + fus_b ----
    int o0 = sl * 3;
    float acc[3];
    #pragma unroll
    for (int j = 0; j < 3; ++j) acc[j] = fus_b[o0 + j];
    const float* w2 = W2 + o0 * DI;
    for (int d = 0; d < DI; ++d) {
        float tv = yv[d * 9 + p8];
        #pragma unroll
        for (int j = 0; j < 3; ++j)
            acc[j] += tv * w2[j * DI + d];
    }
    const float* fw = fus_w + o0 * DI;
    for (int c = 0; c < CC; ++c) {
        float cv = ct[c * 9 + p8];
        #pragma unroll
        for (int j = 0; j < 3; ++j)
            acc[j] += cv * fw[j * DI + c];
    }
    // ---- phase 3: LN + residual ----
    float fs = 0.f, fs2 = 0.f;
    #pragma unroll
    for (int j = 0; j < 3; ++j) { fs += acc[j]; fs2 += acc[j] * acc[j]; }
    ps[sl][p8] = fs; ps2[sl][p8] = fs2;
    __syncthreads();
    float fst = 0.f, fst2 = 0.f;
    #pragma unroll
    for (int i = 0; i < 32; ++i) { fst += ps[i][p8]; fst2 += ps2[i][p8]; }
    float fm = fst * (1.f / 96.f);
    float finv = rsqrtf(fst2 * (1.f / 96.f) - fm * fm + 1e-5f);
    #pragma unroll
    for (int j = 0; j < 3; ++j) {
        int o = o0 + j;
        res[p8 * 97 + o] = (acc[j] - fm) * finv * flg[o] + flb[o];
    }
    __syncthreads();
    const float* xb = x + (b * LL + t0) * CC;
    float* ob = out + (b * LL + t0) * CC;
    for (int e = tid; e < 8 * CC; e += 256) {
        int pl = e / CC, o = e % CC;
        ob[e] = xb[e] + res[pl * 97 + o];
    }
}

extern "C" void kernel_launch(void* const* d_in, const int* in_sizes, int n_in,
                              void* d_out, int out_size, void* d_ws, size_t ws_size,
                              hipStream_t stream) {
    const float* x        = (const float*)d_in[0];
    const float* dw_w     = (const float*)d_in[1];
    const float* dw_b     = (const float*)d_in[2];
    const float* bn1_g    = (const float*)d_in[3];
    const float* bn1_b    = (const float*)d_in[4];
    const float* bn1_m    = (const float*)d_in[5];
    const float* bn1_v    = (const float*)d_in[6];
    const float* pw_w     = (const float*)d_in[7];
    const float* pw_b     = (const float*)d_in[8];
    const float* bn2_g    = (const float*)d_in[9];
    const float* bn2_b    = (const float*)d_in[10];
    const float* bn2_m    = (const float*)d_in[11];
    const float* bn2_v    = (const float*)d_in[12];
    const float* ln_g     = (const float*)d_in[13];
    const float* ln_b     = (const float*)d_in[14];
    const float* ipw      = (const float*)d_in[15];
    const float* conv_w   = (const float*)d_in[16];
    const float* conv_b   = (const float*)d_in[17];
    const float* xpw      = (const float*)d_in[18];
    const float* dtw      = (const float*)d_in[19];
    const float* dtb      = (const float*)d_in[20];
    const float* A_logs   = (const float*)d_in[21];
    const float* Ds       = (const float*)d_in[22];
    const float* ong      = (const float*)d_in[23];
    const float* onb      = (const float*)d_in[24];
    const float* opw      = (const float*)d_in[25];
    const float* fus_w    = (const float*)d_in[26];
    const float* fus_b    = (const float*)d_in[27];
    const float* flg      = (const float*)d_in[28];
    const float* flb      = (const float*)d_in[29];

    float* ws = (float*)d_ws;
    float* conv_out = ws + OFF_CONV;
    float* xm_raw   = ws + OFF_XMRAW;
    float* z_buf    = ws + OFF_Z;
    float* v1       = ws + OFF_V1;
    float* v2       = ws + OFF_V2;
    float* dt_s     = ws + OFF_DT;
    float* B_s      = ws + OFF_BS;
    float* C_s      = ws + OFF_CS;
    float* y_scan   = ws + OFF_Y;
    float* y13t     = ws + OFF_Y13;
    float* W2       = ws + OFF_W2;
    // Aliases (lifetime-disjoint):
    float* cbuf     = y13t;            // kA/kB scratch (dead before scan)
    float* hl_buf   = y13t;            // hlast -> (in-place) hin; dead after k5d;
                                       // k5b then overwrites region with y13t
    float* Tbuf     = xm_raw;          // chunk dt totals (xm_raw dead after kB)
    float* dtr_g    = xm_raw + 262144; // rank-6 dt rows (disjoint from Tbuf; live thru k5d)
    float* negA     = ws + OFF_T;      // t_buf region hosts negA only
    float* out      = (float*)d_out;

    kA<<<dim3(NBLK_K1A + NBLK_K2 + NBLK_K0), dim3(256), 0, stream>>>(
        x, dw_w, dw_b, bn1_g, bn1_b, bn1_m, bn1_v, ln_g, ln_b, ipw,
        fus_w, opw, A_logs, cbuf, xm_raw, z_buf, W2, negA);
    kB<<<dim3(NBLK_K1B + NBLK_K3), dim3(256), 0, stream>>>(
        cbuf, pw_w, pw_b, bn2_g, bn2_b, bn2_m, bn2_v,
        xm_raw, conv_w, conv_b, conv_out, v1, v2);
    k4a_xproj<<<dim3(NT, 4, BZ), dim3(256), 0, stream>>>(v1, v2, xpw, dtr_g, B_s, C_s);
    k4b_dt<<<dim3(NT, 4, BZ), dim3(256), 0, stream>>>(dtr_g, dtw, dtb, dt_s);
    k5a_scan<<<dim3(3 * NCH, 4, BZ), dim3(128), 0, stream>>>(dt_s, B_s, C_s, v1, v2, A_logs,
                                                             y_scan, hl_buf, Tbuf);
    k5c_comb<<<dim3(48, 4, BZ), dim3(64), 0, stream>>>(hl_buf, Tbuf, negA);
    k5d_corr<<<dim3((NCH - 1) * 4, 4, BZ), dim3(256), 0, stream>>>(dtr_g, dtw, dtb, C_s,
                                                             hl_buf, negA, y_scan);
    k5b_tr<<<dim3(BZ * 2 * DI), dim3(256), 0, stream>>>(y_scan, y13t);
    k6_fused<<<dim3(LL / 8, BZ), dim3(256), 0, stream>>>(y_scan, y13t, v1, z_buf,
                                                      Ds, ong, onb, W2, fus_w, fus_b,
                                                      flg, flb, conv_out, x, out);
}

// Round 14
// 343.485 us; speedup vs baseline: 1.0172x; 1.0172x over previous
//
#include <hip/hip_runtime.h>
#include <math.h>

// Problem constants
#define BZ 2
#define HH 56
#define WW 56
#define LL 3136      // 56*56
#define CC 96        // DIM
#define DI 192       // DINNER
#define NS 16        // DSTATE
#define RR 6         // DTRANK
#define NT 49        // LL/64
#define NCH 98       // scan chunks (32 positions each)
#define CH 32        // chunk length

// Merged-launch block counts
#define NBLK_K1A 2352      // (BZ*LL*CC)/256
#define NBLK_K2  784       // NT*8*BZ
#define NBLK_K0  120       // (CC*DI + 4*DI*NS)/256
#define NBLK_K1B 392       // NT*4*BZ
#define NBLK_K3  768       // BZ*DI*2

// Workspace layout (floats)
#define OFF_CONV   0
#define OFF_XMRAW  602112
#define OFF_Z      1806336
#define OFF_V1     3010560
#define OFF_V2     4214784
#define OFF_DT     5419008
#define OFF_BS     10235904
#define OFF_CS     10637312
#define OFF_Y      11038720
#define OFF_Y13    15855616
#define OFF_T      18264064
#define OFF_W2     19468288
// total 19486720 floats = ~78 MB

__device__ __forceinline__ float softplusf(float x) {
    if (x > 20.f) return x;
    return log1pf(__expf(x));
}

// ---------------- kA: merged k1a (dwconv+bn1+relu) | k2 (LN+in_proj) | k0 (prep) -------
__global__ __launch_bounds__(256) void kA(const float* __restrict__ x,
    const float* __restrict__ dw_w, const float* __restrict__ dw_b,
    const float* __restrict__ bn1_g, const float* __restrict__ bn1_b,
    const float* __restrict__ bn1_m, const float* __restrict__ bn1_v,
    const float* __restrict__ ln_g, const float* __restrict__ ln_b,
    const float* __restrict__ ipw,
    const float* __restrict__ fus_w, const float* __restrict__ opw,
    const float* __restrict__ A_logs,
    float* __restrict__ cbuf, float* __restrict__ xm_raw, float* __restrict__ z_buf,
    float* __restrict__ W2, float* __restrict__ negA) {
    int bx = blockIdx.x;
    if (bx < NBLK_K1A) {
        // ---- k1a body ----
        int i = bx * 256 + threadIdx.x;
        if (i >= BZ * LL * CC) return;
        int c = i % CC;
        int bl = i / CC;
        int l = bl % LL, b = bl / LL;
        int h = l / WW, w = l % WW;
        float acc = dw_b[c];
        #pragma unroll
        for (int dy = -1; dy <= 1; ++dy) {
            int hh = h + dy; if (hh < 0 || hh >= HH) continue;
            #pragma unroll
            for (int dx = -1; dx <= 1; ++dx) {
                int ww = w + dx; if (ww < 0 || ww >= WW) continue;
                acc += x[((b * HH + hh) * WW + ww) * CC + c] * dw_w[c * 9 + (dy + 1) * 3 + (dx + 1)];
            }
        }
        float inv = rsqrtf(bn1_v[c] + 1e-5f);
        float v = (acc - bn1_m[c]) * inv * bn1_g[c] + bn1_b[c];
        cbuf[i] = fmaxf(v, 0.f);
    } else if (bx < NBLK_K1A + NBLK_K2) {
        // ---- k2 body ----
        int r = bx - NBLK_K1A;
        int tile = r % NT;
        int og = (r / NT) % 8;
        int b = r / (NT * 8);
        int t0 = tile * 64;
        int lane = threadIdx.x & 63;
        int wv = threadIdx.x >> 6;
        int wvu = __builtin_amdgcn_readfirstlane(wv);
        __shared__ float xt[64 * 97];      // [p][c]
        __shared__ float xn[96 * 65];      // [c][p] normalized
        __shared__ float ps[4][64], ps2[4][64];
        const float* xb = x + (b * LL + t0) * CC;
        for (int e = threadIdx.x; e < 64 * CC; e += 256) {
            int p = e / CC, c = e % CC;
            xt[p * 97 + c] = xb[e];
        }
        __syncthreads();
        float s = 0.f, s2 = 0.f;
        #pragma unroll
        for (int j = 0; j < 24; ++j) {
            float v = xt[lane * 97 + wvu * 24 + j];
            s += v; s2 += v * v;
        }
        ps[wv][lane] = s; ps2[wv][lane] = s2;
        __syncthreads();
        float st = 0.f, st2 = 0.f;
        #pragma unroll
        for (int i = 0; i < 4; ++i) { st += ps[i][lane]; st2 += ps2[i][lane]; }
        float m = st * (1.f / 96.f);
        float inv = rsqrtf(st2 * (1.f / 96.f) - m * m + 1e-5f);
        #pragma unroll
        for (int j = 0; j < 24; ++j) {
            int c = wvu * 24 + j;
            xn[c * 65 + lane] = (xt[lane * 97 + c] - m) * inv * ln_g[c] + ln_b[c];
        }
        __syncthreads();
        float acc[12];
        #pragma unroll
        for (int j = 0; j < 12; ++j) acc[j] = 0.f;
        int o0 = og * 48 + wvu * 12;
        const float* wbase = ipw + o0 * CC;       // uniform -> s_load
        for (int c = 0; c < CC; ++c) {
            float xv = xn[c * 65 + lane];
            #pragma unroll
            for (int j = 0; j < 12; ++j)
                acc[j] += xv * wbase[j * CC + c];
        }
        int p = t0 + lane;
        #pragma unroll
        for (int j = 0; j < 12; ++j) {
            int out = o0 + j;
            if (out < DI) xm_raw[(b * DI + out) * LL + p] = acc[j];
            else          z_buf[(b * DI + (out - DI)) * LL + p] = acc[j];
        }
    } else {
        // ---- k0 body ----
        int i = (bx - NBLK_K1A - NBLK_K2) * 256 + threadIdx.x;
        if (i < CC * DI) {
            int o = i / DI, d = i % DI;
            float acc = 0.f;
            for (int j = 0; j < CC; ++j)
                acc += fus_w[o * DI + CC + j] * opw[j * DI + d];
            W2[i] = acc;
        } else if (i < CC * DI + 4 * DI * NS) {
            int j = i - CC * DI;
            negA[j] = -__expf(A_logs[j]);
        }
    }
}

// ---------------- kB: merged k1b (pw 1x1 + bn2) | k3 (dwconv+SiLU -> v1,v2) -----------
__global__ __launch_bounds__(256) void kB(const float* __restrict__ cbuf,
    const float* __restrict__ pw_w, const float* __restrict__ pw_b,
    const float* __restrict__ bn2_g, const float* __restrict__ bn2_b,
    const float* __restrict__ bn2_m, const float* __restrict__ bn2_v,
    const float* __restrict__ xm_raw,
    const float* __restrict__ conv_w, const float* __restrict__ conv_b,
    float* __restrict__ conv_out, float* __restrict__ v1, float* __restrict__ v2) {
    int bx = blockIdx.x;
    if (bx < NBLK_K1B) {
        // ---- k1b body ----
        int tile = bx % NT;
        int og = (bx / NT) % 4;
        int b = bx / (NT * 4);
        int t0 = tile * 64;
        int lane = threadIdx.x & 63;
        int wvu = __builtin_amdgcn_readfirstlane(threadIdx.x >> 6);
        __shared__ float ct[CC * 65];      // [c][p]
        __shared__ float res[64 * 25];     // [p][24 outs + pad]
        const float* cb = cbuf + (b * LL + t0) * CC;
        for (int e = threadIdx.x; e < 64 * CC; e += 256) {
            int p = e / CC, c = e % CC;
            ct[c * 65 + p] = cb[e];
        }
        __syncthreads();
        int o0 = og * 24 + wvu * 6;
        float acc[6];
        const float* pb = pw_b + o0;
        #pragma unroll
        for (int j = 0; j < 6; ++j) acc[j] = pb[j];
        const float* wb = pw_w + o0 * CC;              // uniform -> s_load
        for (int c = 0; c < CC; ++c) {
            float xv = ct[c * 65 + lane];
            #pragma unroll
            for (int j = 0; j < 6; ++j)
                acc[j] += xv * wb[j * CC + c];
        }
        #pragma unroll
        for (int j = 0; j < 6; ++j) {
            int o = o0 + j;
            float inv = rsqrtf(bn2_v[o] + 1e-5f);
            res[lane * 25 + wvu * 6 + j] = (acc[j] - bn2_m[o]) * inv * bn2_g[o] + bn2_b[o];
        }
        __syncthreads();
        float* ob = conv_out + (b * LL + t0) * CC + og * 24;
        for (int e = threadIdx.x; e < 64 * 24; e += 256) {
            int pl = e / 24, o = e % 24;
            ob[pl * CC + o] = res[pl * 25 + o];
        }
    } else {
        // ---- k3 body ----
        int r = bx - NBLK_K1B;
        int bd = r % (BZ * DI);
        int half = r / (BZ * DI);
        int d = bd % DI;
        int h0 = half * 28;
        __shared__ float tile3[28 * 57];
        const float* src = xm_raw + bd * LL;
        float wloc[9];
        #pragma unroll
        for (int i = 0; i < 9; ++i) wloc[i] = conv_w[d * 9 + i];
        float bias = conv_b[d];
        for (int e = threadIdx.x; e < 28 * WW; e += 256) {
            int hl = e / WW, w = e % WW;
            int h = h0 + hl;
            float acc = bias;
            #pragma unroll
            for (int dy = -1; dy <= 1; ++dy) {
                int hh = h + dy; if (hh < 0 || hh >= HH) continue;
                #pragma unroll
                for (int dx = -1; dx <= 1; ++dx) {
                    int ww = w + dx; if (ww < 0 || ww >= WW) continue;
                    acc += src[hh * WW + ww] * wloc[(dy + 1) * 3 + (dx + 1)];
                }
            }
            float sig = 1.f / (1.f + __expf(-acc));
            float v = acc * sig;
            v1[bd * LL + h * WW + w] = v;
            tile3[hl * 57 + w] = v;
        }
        __syncthreads();
        for (int e = threadIdx.x; e < 28 * WW; e += 256) {
            int w = e / 28, hl = e % 28;
            v2[bd * LL + w * HH + h0 + hl] = tile3[hl * 57 + w];
        }
    }
}

// ---------------- K4a: x_proj — 4-wave blocks, no LDS, 10 rows/wave ----------------
__global__ __launch_bounds__(256) void k4a_xproj(const float* __restrict__ v1,
    const float* __restrict__ v2, const float* __restrict__ xpw,
    float* __restrict__ dtr_g, float* __restrict__ B_s, float* __restrict__ C_s) {
    int tile = blockIdx.x;
    int k = blockIdx.y, b = blockIdx.z;
    int lane = threadIdx.x & 63;
    int wvu = __builtin_amdgcn_readfirstlane(threadIdx.x >> 6);
    int t0 = tile * 64;
    int r0 = wvu * 10; if (r0 > 28) r0 = 28;
    const float* src = ((k & 1) == 0 ? v1 : v2) + b * DI * LL + t0;
    float acc[10];
    #pragma unroll
    for (int i = 0; i < 10; ++i) acc[i] = 0.f;
    const float* wbase = xpw + (k * 38 + r0) * DI;   // uniform -> s_load
    for (int d = 0; d < DI; ++d) {
        float xv = src[d * LL + lane];
        #pragma unroll
        for (int i = 0; i < 10; ++i)
            acc[i] += xv * wbase[i * DI + d];
    }
    int bk = b * 4 + k;
    int p = t0 + lane;
    #pragma unroll
    for (int i = 0; i < 10; ++i) {
        int c = r0 + i;
        if (c < RR) {
            dtr_g[(bk * RR + c) * LL + p] = acc[i];
        } else if (c < RR + NS) {
            B_s[(bk * NS + (c - RR)) * LL + p] = acc[i];
        } else {
            C_s[(bk * NS + (c - RR - NS)) * LL + p] = acc[i];
        }
    }
}

// ---------------- K4b: dt_proj + softplus (streaming write) ----------------
__global__ __launch_bounds__(256) void k4b_dt(const float* __restrict__ dtr_g,
    const float* __restrict__ dtw, const float* __restrict__ dtb,
    float* __restrict__ dt_s) {
    int t0 = blockIdx.x * 64;
    int k = blockIdx.y, b = blockIdx.z;
    int lane = threadIdx.x & 63;
    int wvu = __builtin_amdgcn_readfirstlane(threadIdx.x >> 6);
    int bk = b * 4 + k;
    int p = t0 + lane;
    float r[RR];
    #pragma unroll
    for (int i = 0; i < RR; ++i) r[i] = dtr_g[(bk * RR + i) * LL + p];
    for (int i = 0; i < 48; ++i) {
        int d = wvu * 48 + i;
        float a = dtb[k * DI + d];
        const float* wr = dtw + (k * DI + d) * RR;   // uniform -> s_load
        #pragma unroll
        for (int q = 0; q < RR; ++q)
            a += r[q] * wr[q];
        dt_s[(bk * DI + d) * LL + p] = softplusf(a);
    }
}

// ---------------- K5a: scan phase 1 — streamed dt, 1 chunk/block, scalar y-flush ------
__global__ __launch_bounds__(128, 4) void k5a_scan(const float* __restrict__ dt_s,
    const float* __restrict__ B_s, const float* __restrict__ C_s,
    const float* __restrict__ v1, const float* __restrict__ v2,
    const float* __restrict__ A_logs, float* __restrict__ y_scan,
    float* __restrict__ hl_buf, float* __restrict__ Tbuf) {
    int bx = blockIdx.x;
    int dg = bx % 3, c = bx / 3;
    int k = blockIdx.y, b = blockIdx.z;
    int bk = b * 4 + k;
    int tid = threadIdx.x;
    int lane = tid & 63;
    int wvu = __builtin_amdgcn_readfirstlane(tid >> 6);   // n-half: 0 or 1
    int d0 = dg * 64, d = d0 + lane;
    bool fwd = (k < 2);
    int s0 = fwd ? c * CH : (LL - (c + 1) * CH);
    __shared__ float dtl[64 * 32];                 // [row][ s ^ (row&31) ]
    __shared__ float ul[64 * 32];                  // du = dt*u, same swizzle
    __shared__ alignas(16) float bc[32 * 32];      // [s][ n ^ ((s&7)<<2) ]
    float Ae[8];
    const float* ap = A_logs + (k * DI + d) * NS + wvu * 8;
    #pragma unroll
    for (int n = 0; n < 8; ++n) Ae[n] = -__expf(ap[n]) * 1.442695040888963f;
    const float* dtp = dt_s + (bk * DI + d0) * LL + s0;
    const float* up  = ((k & 1) == 0 ? v1 : v2) + (b * DI + d0) * LL + s0;
    // ---- stage dt & du: float4 global loads, swizzled scalar LDS writes ----
    #pragma unroll
    for (int q = 0; q < 4; ++q) {
        int e = q * 128 + tid;          // 0..511
        int row = e >> 3;               // 0..63
        int p4 = (e & 7) << 2;          // 0,4,...,28
        float4 dv = *(const float4*)(dtp + row * LL + p4);
        float4 uv = *(const float4*)(up + row * LL + p4);
        float dvv[4] = {dv.x, dv.y, dv.z, dv.w};
        float uvv[4] = {uv.x, uv.y, uv.z, uv.w};
        int rsw = row & 31;
        #pragma unroll
        for (int t = 0; t < 4; ++t) {
            int s = fwd ? (p4 + t) : (31 - (p4 + t));
            dtl[row * 32 + (s ^ rsw)] = dvv[t];
            ul [row * 32 + (s ^ rsw)] = dvv[t] * uvv[t];
        }
    }
    // ---- stage B/C ----
    #pragma unroll
    for (int q = 0; q < 2; ++q) {
        int e = q * 128 + tid;          // 0..255
        int row = e >> 3;               // 0..31 (B: 0..15, C: 16..31)
        int p4 = (e & 7) << 2;
        const float* src = (row < 16 ? B_s + (bk * NS + row) * LL
                                     : C_s + (bk * NS + (row - 16)) * LL) + s0 + p4;
        float4 v = *(const float4*)src;
        float vv[4] = {v.x, v.y, v.z, v.w};
        #pragma unroll
        for (int t = 0; t < 4; ++t) {
            int s = fwd ? (p4 + t) : (31 - (p4 + t));
            bc[s * 32 + (row ^ ((s & 7) << 2))] = vv[t];
        }
    }
    __syncthreads();
    float h[8];
    #pragma unroll
    for (int n = 0; n < 8; ++n) h[n] = 0.f;
    float cum = 0.f;
    int lbase = lane * 32;
    int lsw = lane & 31;
    int w8 = wvu * 8;
    #pragma unroll
    for (int seg = 0; seg < 4; ++seg) {
        float yv_[8];
        #pragma unroll
        for (int jj = 0; jj < 8; ++jj) {
            int j = seg * 8 + jj;
            float dtv = dtl[lbase + (j ^ lsw)];
            float du  = ul [lbase + (j ^ lsw)];
            cum += dtv;
            int cswz = (j & 7) << 2;
            const float* rb0 = &bc[j * 32 + ( w8       ^ cswz)];
            const float* rb1 = &bc[j * 32 + ((w8 +  4) ^ cswz)];
            const float* rc0 = &bc[j * 32 + ((w8 + 16) ^ cswz)];
            const float* rc1 = &bc[j * 32 + ((w8 + 20) ^ cswz)];
            float4 b0 = *(const float4*)rb0, b1 = *(const float4*)rb1;
            float4 c0 = *(const float4*)rc0, c1 = *(const float4*)rc1;
            float bv[8] = {b0.x, b0.y, b0.z, b0.w, b1.x, b1.y, b1.z, b1.w};
            float cv[8] = {c0.x, c0.y, c0.z, c0.w, c1.x, c1.y, c1.z, c1.w};
            float y = 0.f;
            #pragma unroll
            for (int n = 0; n < 8; ++n) {
                h[n] = exp2f(dtv * Ae[n]) * h[n] + du * bv[n];
                y += h[n] * cv[n];
            }
            yv_[jj] = y;
        }
        // slots seg*8..seg*8+7 are dead once BOTH waves passed them
        __syncthreads();
        float* dst = (wvu == 0) ? dtl : ul;
        #pragma unroll
        for (int jj = 0; jj < 8; ++jj) {
            int j = seg * 8 + jj;
            dst[lbase + (j ^ lsw)] = yv_[jj];
        }
    }
    __syncthreads();
    // ---- flush y: scalar stores, 2 rows x 32 consecutive lanes per instruction ----
    float* yp = y_scan + (bk * DI + d0) * LL + s0;
    int pr = tid >> 5, pc = tid & 31;                 // pr 0..3
    int sg = fwd ? pc : (31 - pc);                    // scan-order slot of global pos pc
    #pragma unroll
    for (int i = 0; i < 16; ++i) {
        int row = i * 4 + pr;
        int rsw = row & 31;
        yp[row * LL + pc] = dtl[row * 32 + (sg ^ rsw)] + ul[row * 32 + (sg ^ rsw)];
    }
    // hlast: each wave owns its 8 n-states
    float4* hp4 = (float4*)(hl_buf + (bk * NCH + c) * (DI * NS) + d * NS + wvu * 8);
    hp4[0] = make_float4(h[0], h[1], h[2], h[3]);
    hp4[1] = make_float4(h[4], h[5], h[6], h[7]);
    if (wvu == 0) Tbuf[(bk * NCH + c) * DI + d] = cum;
}

// ---------------- K5c: scan phase 2 — serial chunk combine, prefetch depth 8 ----------
__global__ __launch_bounds__(64) void k5c_comb(float* __restrict__ hl_buf,
    const float* __restrict__ Tbuf, const float* __restrict__ negA) {
    int dg = blockIdx.x, k = blockIdx.y, b = blockIdx.z;
    int lane = threadIdx.x, dl = lane >> 4, n = lane & 15;
    int d = dg * 4 + dl;
    int bk = b * 4 + k;
    const int HS = DI * NS;
    float Av = negA[(k * DI + d) * NS + n];
    float* hp = hl_buf + (bk * NCH) * HS + dg * 64 + lane;
    const float* Tp = Tbuf + (bk * NCH) * DI + d;
    float hl[8], T[8];
    #pragma unroll
    for (int i = 0; i < 8; ++i) { hl[i] = hp[i * HS]; T[i] = Tp[i * DI]; }
    float H = 0.f;
    for (int cb = 0; cb < 96; cb += 8) {
        #pragma unroll
        for (int i = 0; i < 8; ++i) {
            int c = cb + i;
            float hlv = hl[i], Tv = T[i];
            int nc = c + 8;
            if (nc < NCH) { hl[i] = hp[nc * HS]; T[i] = Tp[nc * DI]; }
            hp[c * HS] = H;
            H = hlv + __expf(Av * Tv) * H;
        }
    }
    hp[96 * HS] = H;
    H = hl[0] + __expf(Av * T[0]) * H;
    hp[97 * HS] = H;
}

// ---------------- K5d: scan phase 3 — parallel correction, d-split x4 ----------
__global__ __launch_bounds__(256) void k5d_corr(const float* __restrict__ dtr_g,
    const float* __restrict__ dtw, const float* __restrict__ dtb,
    const float* __restrict__ C_s, const float* __restrict__ hin,
    const float* __restrict__ negA, float* __restrict__ y_scan) {
    int t  = blockIdx.x % (NCH - 1);
    int ds = blockIdx.x / (NCH - 1);   // 0..3 d-split
    int k = blockIdx.y, b = blockIdx.z;
    bool fwd = (k < 2);
    int c  = fwd ? (t + 1) : (NCH - 1 - t);
    int s0 = fwd ? (t + 1) * CH : t * CH;
    int p32 = threadIdx.x & 31, sl = threadIdx.x >> 5;
    int bk = b * 4 + k;
    __shared__ float c_l[16 * 33];
    for (int e = threadIdx.x; e < 16 * CH; e += 256) {
        int n = e >> 5, s = e & 31;
        c_l[n * 33 + s] = C_s[(bk * NS + n) * LL + s0 + s];
    }
    const float* rp = dtr_g + (bk * RR) * LL + s0 + p32;
    float r[RR];
    #pragma unroll
    for (int q = 0; q < RR; ++q) r[q] = rp[q * LL];
    __syncthreads();
    for (int j = 0; j < 6; ++j) {
        int d = ds * 48 + sl * 6 + j;
        int dd = k * DI + d;
        const float* wr = dtw + dd * RR;
        float a = dtb[dd];
        #pragma unroll
        for (int q = 0; q < RR; ++q)
            a += r[q] * wr[q];
        float dtv = softplusf(a);
        float cum = dtv;
        if (fwd) {
            #pragma unroll
            for (int off = 1; off < 32; off <<= 1) {
                float o = __shfl_up(cum, off, 32);
                if (p32 >= off) cum += o;
            }
        } else {
            #pragma unroll
            for (int off = 1; off < 32; off <<= 1) {
                float o = __shfl_down(cum, off, 32);
                if (p32 < 32 - off) cum += o;
            }
        }
        const float* hp = hin + (bk * NCH + c) * (DI * NS) + d * 16;
        const float* ap = negA + (k * DI + d) * NS;
        float4 h0 = *(const float4*)(hp);
        float4 h1 = *(const float4*)(hp + 4);
        float4 h2 = *(const float4*)(hp + 8);
        float4 h3 = *(const float4*)(hp + 12);
        float4 a0 = *(const float4*)(ap);
        float4 a1 = *(const float4*)(ap + 4);
        float4 a2 = *(const float4*)(ap + 8);
        float4 a3 = *(const float4*)(ap + 12);
        float hv[16] = {h0.x, h0.y, h0.z, h0.w, h1.x, h1.y, h1.z, h1.w,
                        h2.x, h2.y, h2.z, h2.w, h3.x, h3.y, h3.z, h3.w};
        float av[16] = {a0.x, a0.y, a0.z, a0.w, a1.x, a1.y, a1.z, a1.w,
                        a2.x, a2.y, a2.z, a2.w, a3.x, a3.y, a3.z, a3.w};
        float acc = 0.f;
        #pragma unroll
        for (int n = 0; n < 16; ++n) {
            acc += c_l[n * 33 + p32] * __expf(av[n] * cum) * hv[n];
        }
        y_scan[(bk * DI + d) * LL + s0 + p32] += acc;
    }
}

// ---------------- K5b: transpose y for k=1,3 (coalesced both ways via LDS tile) -------
__global__ __launch_bounds__(256) void k5b_tr(const float* __restrict__ y_scan,
                                              float* __restrict__ y13t) {
    int idx = blockIdx.x;
    int d = idx % DI;
    int bk = idx / DI;
    int kk = bk % 2, b = bk / 2;
    int k = (kk == 0) ? 1 : 3;
    __shared__ float tile[HH * 57];
    const float* src = y_scan + ((b * 4 + k) * DI + d) * LL;
    for (int e = threadIdx.x; e < LL; e += 256) {
        int w = e / HH, h = e % HH;
        tile[h * 57 + w] = src[e];
    }
    __syncthreads();
    float* dst = y13t + idx * LL;
    for (int e = threadIdx.x; e < LL; e += 256) {
        int h = e / WW, w = e % WW;
        dst[e] = tile[h * 57 + w];
    }
}

// ---------------- K6: fused gather + out_norm + gate + fus-matmul + LN + residual ------
// XCD-aware tile swizzle: consecutive 8-position tiles (32B row segments) are
// assigned to the SAME XCD (tile = (bid&7)*49 + bid>>3; 392 = 8*49, bijective),
// so 128B lines shared by 4 neighbor tiles become same-L2 hits instead of
// being fetched by up to 4 different XCDs (R13: FETCH 59.3 MB vs 36 logical).
__global__ __launch_bounds__(256) void k6_fused(const float* __restrict__ y_scan,
    const float* __restrict__ y13t, const float* __restrict__ v1,
    const float* __restrict__ z_buf, const float* __restrict__ Ds,
    const float* __restrict__ ong, const float* __restrict__ onb,
    const float* __restrict__ W2, const float* __restrict__ fus_w,
    const float* __restrict__ fus_b, const float* __restrict__ flg,
    const float* __restrict__ flb, const float* __restrict__ conv_out,
    const float* __restrict__ x, float* __restrict__ out) {
    int bid = blockIdx.x;                       // 0..391
    int tile = (bid & 7) * 49 + (bid >> 3);     // bijective XCD swizzle (392 = 8*49)
    int t0 = tile * 8;
    int b = blockIdx.y;
    int tid = threadIdx.x;
    int p8 = tid & 7, sl = tid >> 3;   // sl 0..31
    int p = t0 + p8;
    __shared__ float yv[DI * 9];       // val -> (in place) gated t, [d][p8+pad]
    __shared__ float ct[CC * 9];       // conv_out [c][p8+pad]
    __shared__ float res[8 * 97];      // normalized fused output [p8][o]
    __shared__ float ps[32][8], ps2[32][8];
    // stage conv_out (for phase 2)
    const float* cb = conv_out + (b * LL + t0) * CC;
    for (int e = tid; e < 8 * CC; e += 256) {
        int pp = e / CC, c = e % CC;
        ct[c * 9 + pp] = cb[e];
    }
    // ---- phase 1: gather 4 dirs + D*u ----
    float s = 0.f, s2 = 0.f;
    for (int j = 0; j < 6; ++j) {
        int d = sl * 6 + j;
        float dsum = Ds[d] + Ds[DI + d] + Ds[2 * DI + d] + Ds[3 * DI + d];
        float val = y_scan[((b * 4 + 0) * DI + d) * LL + p]
                  + y_scan[((b * 4 + 2) * DI + d) * LL + p]
                  + y13t[((b * 2 + 0) * DI + d) * LL + p]
                  + y13t[((b * 2 + 1) * DI + d) * LL + p]
                  + v1[(b * DI + d) * LL + p] * dsum;
        yv[d * 9 + p8] = val;
        s += val; s2 += val * val;
    }
    ps[sl][p8] = s; ps2[sl][p8] = s2;
    __syncthreads();
    float st = 0.f, st2 = 0.f;
    #pragma unroll
    for (int i = 0; i < 32; ++i) { st += ps[i][p8]; st2 += ps2[i][p8]; }
    float m = st * (1.f / 192.f);
    float inv = rsqrtf(st2 * (1.f / 192.f) - m * m + 1e-5f);
    for (int j = 0; j < 6; ++j) {
        int d = sl * 6 + j;
        float val = (yv[d * 9 + p8] - m) * inv * ong[d] + onb[d];
        float zz = z_buf[(b * DI + d) * LL + p];
        float sig = 1.f / (1.f + __expf(-zz));
        yv[d * 9 + p8] = val * zz * sig;       // gated t, in place
    }
    __syncthreads();
    // ---- phase 2: fused matmul (t@W2 | conv_out@fus_w[:96]) + fus_b ----
    int o0 = sl * 3;
    float acc[3];
    #pragma unroll
    for (int j = 0; j < 3; ++j) acc[j] = fus_b[o0 + j];
    const float* w2 = W2 + o0 * DI;
    for (int d = 0; d < DI; ++d) {
        float tv = yv[d * 9 + p8];
        #pragma unroll
        for (int j = 0; j < 3; ++j)
            acc[j] += tv * w2[j * DI + d];
    }
    const float* fw = fus_w + o0 * DI;
    for (int c = 0; c < CC; ++c) {
        float cv = ct[c * 9 + p8];
        #pragma unroll
        for (int j = 0; j < 3; ++j)
            acc[j] += cv * fw[j * DI + c];
    }
    // ---- phase 3: LN + residual ----
    float fs = 0.f, fs2 = 0.f;
    #pragma unroll
    for (int j = 0; j < 3; ++j) { fs += acc[j]; fs2 += acc[j] * acc[j]; }
    ps[sl][p8] = fs; ps2[sl][p8] = fs2;
    __syncthreads();
    float fst = 0.f, fst2 = 0.f;
    #pragma unroll
    for (int i = 0; i < 32; ++i) { fst += ps[i][p8]; fst2 += ps2[i][p8]; }
    float fm = fst * (1.f / 96.f);
    float finv = rsqrtf(fst2 * (1.f / 96.f) - fm * fm + 1e-5f);
    #pragma unroll
    for (int j = 0; j < 3; ++j) {
        int o = o0 + j;
        res[p8 * 97 + o] = (acc[j] - fm) * finv * flg[o] + flb[o];
    }
    __syncthreads();
    const float* xb = x + (b * LL + t0) * CC;
    float* ob = out + (b * LL + t0) * CC;
    for (int e = tid; e < 8 * CC; e += 256) {
        int pl = e / CC, o = e % CC;
        ob[e] = xb[e] + res[pl * 97 + o];
    }
}

extern "C" void kernel_launch(void* const* d_in, const int* in_sizes, int n_in,
                              void* d_out, int out_size, void* d_ws, size_t ws_size,
                              hipStream_t stream) {
    const float* x        = (const float*)d_in[0];
    const float* dw_w     = (const float*)d_in[1];
    const float* dw_b     = (const float*)d_in[2];
    const float* bn1_g    = (const float*)d_in[3];
    const float* bn1_b    = (const float*)d_in[4];
    const float* bn1_m    = (const float*)d_in[5];
    const float* bn1_v    = (const float*)d_in[6];
    const float* pw_w     = (const float*)d_in[7];
    const float* pw_b     = (const float*)d_in[8];
    const float* bn2_g    = (const float*)d_in[9];
    const float* bn2_b    = (const float*)d_in[10];
    const float* bn2_m    = (const float*)d_in[11];
    const float* bn2_v    = (const float*)d_in[12];
    const float* ln_g     = (const float*)d_in[13];
    const float* ln_b     = (const float*)d_in[14];
    const float* ipw      = (const float*)d_in[15];
    const float* conv_w   = (const float*)d_in[16];
    const float* conv_b   = (const float*)d_in[17];
    const float* xpw      = (const float*)d_in[18];
    const float* dtw      = (const float*)d_in[19];
    const float* dtb      = (const float*)d_in[20];
    const float* A_logs   = (const float*)d_in[21];
    const float* Ds       = (const float*)d_in[22];
    const float* ong      = (const float*)d_in[23];
    const float* onb      = (const float*)d_in[24];
    const float* opw      = (const float*)d_in[25];
    const float* fus_w    = (const float*)d_in[26];
    const float* fus_b    = (const float*)d_in[27];
    const float* flg      = (const float*)d_in[28];
    const float* flb      = (const float*)d_in[29];

    float* ws = (float*)d_ws;
    float* conv_out = ws + OFF_CONV;
    float* xm_raw   = ws + OFF_XMRAW;
    float* z_buf    = ws + OFF_Z;
    float* v1       = ws + OFF_V1;
    float* v2       = ws + OFF_V2;
    float* dt_s     = ws + OFF_DT;
    float* B_s      = ws + OFF_BS;
    float* C_s      = ws + OFF_CS;
    float* y_scan   = ws + OFF_Y;
    float* y13t     = ws + OFF_Y13;
    float* W2       = ws + OFF_W2;
    // Aliases (lifetime-disjoint):
    float* cbuf     = y13t;            // kA/kB scratch (dead before scan)
    float* hl_buf   = y13t;            // hlast -> (in-place) hin; dead after k5d;
                                       // k5b then overwrites region with y13t
    float* Tbuf     = xm_raw;          // chunk dt totals (xm_raw dead after kB)
    float* dtr_g    = xm_raw + 262144; // rank-6 dt rows (disjoint from Tbuf; live thru k5d)
    float* negA     = ws + OFF_T;      // t_buf region hosts negA only
    float* out      = (float*)d_out;

    kA<<<dim3(NBLK_K1A + NBLK_K2 + NBLK_K0), dim3(256), 0, stream>>>(
        x, dw_w, dw_b, bn1_g, bn1_b, bn1_m, bn1_v, ln_g, ln_b, ipw,
        fus_w, opw, A_logs, cbuf, xm_raw, z_buf, W2, negA);
    kB<<<dim3(NBLK_K1B + NBLK_K3), dim3(256), 0, stream>>>(
        cbuf, pw_w, pw_b, bn2_g, bn2_b, bn2_m, bn2_v,
        xm_raw, conv_w, conv_b, conv_out, v1, v2);
    k4a_xproj<<<dim3(NT, 4, BZ), dim3(256), 0, stream>>>(v1, v2, xpw, dtr_g, B_s, C_s);
    k4b_dt<<<dim3(NT, 4, BZ), dim3(256), 0, stream>>>(dtr_g, dtw, dtb, dt_s);
    k5a_scan<<<dim3(3 * NCH, 4, BZ), dim3(128), 0, stream>>>(dt_s, B_s, C_s, v1, v2, A_logs,
                                                             y_scan, hl_buf, Tbuf);
    k5c_comb<<<dim3(48, 4, BZ), dim3(64), 0, stream>>>(hl_buf, Tbuf, negA);
    k5d_corr<<<dim3((NCH - 1) * 4, 4, BZ), dim3(256), 0, stream>>>(dtr_g, dtw, dtb, C_s,
                                                             hl_buf, negA, y_scan);
    k5b_tr<<<dim3(BZ * 2 * DI), dim3(256), 0, stream>>>(y_scan, y13t);
    k6_fused<<<dim3(LL / 8, BZ), dim3(256), 0, stream>>>(y_scan, y13t, v1, z_buf,
                                                      Ds, ong, onb, W2, fus_w, fus_b,
                                                      flg, flb, conv_out, x, out);
}